// Round 3
// baseline (92.954 us; speedup 1.0000x reference)
//
#include <hip/hip_runtime.h>
#include <hip/hip_bf16.h>

// Problem constants (fixed): n=4, b=8192, a=32, c_in=32, d_out=32,
// n_basis=36 (4 radii x 9 SH), ck=1152.
// inputs: [0] input (4,32,8192) f32, [1] coords (4,8192,3) f32,
//         [2] relative_mask (4,8192,32) f32, [3] W (32,32,36) f32,
//         [4] neighbors (4,8192,32) i32
// output: (4,32,8192) f32
//
// R13 = R12 + persistent-block software pipeline (T14):
//  - grid 512 blocks (2/CU exactly), each block loops 4 point-tiles.
//  - tile t+1 neigh/rmask/coords loads issued during tile t phase 1;
//    tile t+1 feat gathers issued during tile t phase 2 -> the ~1300cy
//    global chain hides under compute + barriers.
//  - idxs LDS roundtrip replaced by ds_bpermute (idx redistribution is a
//    wave-internal broadcast) -> shorter gather critical path, -1KB LDS.
//  - W-fragments (wf0..wf8) loaded once per block, amortized over 4 tiles.
//  - Mb writes split A/B right after their MFMAs to cap live D-regs.
// Phase structure per tile otherwise identical to R12 (16 pts/tile, 512 thr,
// 2 passes/wave, bas stride 44, fully-unrolled phase 2).

typedef _Float16 f16x8 __attribute__((ext_vector_type(8)));
typedef _Float16 f16x4 __attribute__((ext_vector_type(4)));
typedef __fp16   h16x2 __attribute__((ext_vector_type(2)));
typedef float    f32x4 __attribute__((ext_vector_type(4)));
typedef unsigned int u32;

__device__ __forceinline__ u32 pk16(float a, float b) {
    union { h16x2 v; u32 u; } cv;
    cv.v = __builtin_amdgcn_cvt_pkrtz(a, b);
    return cv.u;
}
__device__ __forceinline__ unsigned short f16bits(float v) {
    const _Float16 hv = (_Float16)v;
    return __builtin_bit_cast(unsigned short, hv);
}

#define BAS_STRIDE 44   // u16 per phys row (88B, b64-aligned, reads <=2-way)

// geometry: SH l=0..2 and the h-half radial pair (mask folded in)
__device__ __forceinline__ void geom(float dx, float dy, float dz, float msk, int h_,
                                     float Y[9], float& rbA, float& rbB) {
    const float d2  = dx * dx + dy * dy + dz * dz;
    const float inv = rsqrtf(d2 + 1e-16f);   // == 1/(r+1e-8) within f16 eps; exact at d2=0
    const float r   = d2 * inv;
    const float x = dx * inv, y = dy * inv, z = dz * inv;
    Y[0] = 0.28209479f;
    Y[1] = 0.48860251f * x;
    Y[2] = 0.48860251f * y;
    Y[3] = 0.48860251f * z;
    Y[4] = 1.09254843f * x * y;
    Y[5] = 1.09254843f * y * z;
    Y[6] = 0.31539157f * (3.0f * z * z - 1.0f);
    Y[7] = 1.09254843f * x * z;
    Y[8] = 0.54627421f * (x * x - y * y);
    const float sA = r - (h_ ? 1.5f : 0.5f);
    const float sB = r - (h_ ? 2.0f : 1.0f);
    rbA = __expf(sA * sA * -4.0f) * msk;   // exp(-((r-c)/0.5)^2) = exp(-4 s^2)
    rbB = __expf(sB * sB * -4.0f) * msk;
}

// per-lane idx broadcast (lane (q,l15) needs neighbor q*8+j, held by lane q*8+j)
__device__ __forceinline__ void gather16(const unsigned short* __restrict__ inp_n,
                                         int q, int l15, int idxA, int idxB,
                                         u32* gA, u32* gB) {
    #pragma unroll
    for (int j = 0; j < 8; ++j) {
        const int riA = __builtin_amdgcn_ds_bpermute((((q << 3) + j) << 2), idxA);
        gA[j] = *(const u32*)(inp_n + (((unsigned)riA) << 5) + (l15 << 1));
    }
    #pragma unroll
    for (int j = 0; j < 8; ++j) {
        const int riB = __builtin_amdgcn_ds_bpermute((((q << 3) + j) << 2), idxB);
        gB[j] = *(const u32*)(inp_n + (((unsigned)riB) << 5) + (l15 << 1));
    }
}

// ---------------- prep: LDS-tiled transpose (f32 -> f16, c-interleaved) + W frags
// inp_t16 row layout (32 u16 per point): pos = 2*(c&15) + (c>>4), i.e.
// [c0,c16,c1,c17,...] so u32 @ 4*l15 = (lo: c=l15, hi: c=l15+16).
// Wfrag[t], t = ((kt*2+dt)*64 + l)*8 + j  holds  W[d][c*36 + k'] as f16, where
// d = dt*16 + (l&15), c = (l>>4)*8+j, k' = kt.
// coords4[p] = float4(x,y,z,0) for point p (one dwordx4 gather in main).
__global__ __launch_bounds__(256) void prep_kernel(
    const float* __restrict__ inp, const float* __restrict__ W,
    const float* __restrict__ coords,
    unsigned short* __restrict__ inp_t16, unsigned short* __restrict__ Wfrag,
    float* __restrict__ coords4)
{
    if (blockIdx.x < 1024) {
        __shared__ float T[32][33];
        const int n  = blockIdx.x >> 8;
        const int b0 = (blockIdx.x & 255) << 5;
        const int bx = threadIdx.x & 31;
        const int cy = threadIdx.x >> 5;   // 0..7
        #pragma unroll
        for (int r = 0; r < 4; ++r) {
            const int cc = cy + r * 8;
            T[bx][cc] = inp[((n << 5) + cc) * 8192 + b0 + bx];
        }
        __syncthreads();
        const int cpos = ((bx & 15) << 1) | (bx >> 4);   // interleaved column
        #pragma unroll
        for (int r = 0; r < 4; ++r) {
            const int by = cy + r * 8;
            inp_t16[((n << 13) + b0 + by) * 32 + cpos] = f16bits(T[by][bx]);
        }
    } else if (blockIdx.x < 1168) {
        const int t = (blockIdx.x - 1024) * 256 + threadIdx.x;   // 0..36863
        if (t < 36 * 2 * 64 * 8) {
            const int j  = t & 7;
            const int l  = (t >> 3) & 63;
            const int dt = (t >> 9) & 1;
            const int kt = t >> 10;                  // k' = 0..35
            const int d  = dt * 16 + (l & 15);
            const int c  = ((l >> 4) << 3) + j;
            Wfrag[t] = f16bits(W[d * 1152 + c * 36 + kt]);
        }
    } else {
        const int t = (blockIdx.x - 1168) * 256 + threadIdx.x;   // 0..32767
        f32x4 v;
        v[0] = coords[3 * t + 0];
        v[1] = coords[3 * t + 1];
        v[2] = coords[3 * t + 2];
        v[3] = 0.0f;
        *(f32x4*)(coords4 + ((size_t)t << 2)) = v;
    }
}

// ---------------- main fused kernel: 512 threads, persistent over 4 tiles ----------
__global__ __launch_bounds__(512, 4) void se3_main(
    const unsigned short* __restrict__ inp_t16, const float* __restrict__ coords4,
    const float* __restrict__ rmask, const int* __restrict__ neigh,
    const unsigned short* __restrict__ Wfrag, float* __restrict__ out)
{
    // Mb[k'=0..35][p=0..15][c=0..31] f16; p-row 72B, plane 1160B (580 us, 8B pad).
    __shared__ __align__(16) unsigned short Mb_s[36 * 580];          // 41,760 B
    // basis^T per wave: phys = 2t + h interleave, 37 rows x 44 us.
    __shared__ __align__(16) unsigned short bas[8][37 * BAS_STRIDE]; // 26,048 B
    __shared__ __align__(16) float Cp[8 * 64 * 4];                   //  8,192 B
    // total 76,000 B -> 2 blocks/CU = 16 waves/CU

    const int tid  = threadIdx.x;
    const int lane = tid & 63;
    const int w    = tid >> 6;      // wave 0..7
    const int l15  = lane & 15;
    const int q    = lane >> 4;     // 0..3
    const int a_   = lane & 31;
    const int h_   = lane >> 5;

    // XCD-aware swizzle: XCD pair {2n,2n+1} serves batch n. 512 blocks total.
    const int blk = blockIdx.x;
    const int n_  = (blk & 7) >> 1;
    const int pos = ((blk >> 3) << 1) | (blk & 1);   // 0..127 per n_
    const int nbase_pt = n_ << 13;
    const unsigned short* __restrict__ inp_n = inp_t16 + ((size_t)n_ << 18);

    unsigned short* basw = &bas[w][0];

    // ---- this wave's 9 phase-2 W-fragments, loaded ONCE per block ----
    const int dt  = w >> 2;       // 0,1
    const int seg = w & 3;        // 9 kt-steps each
    const int kt0 = seg * 9;
    f16x8 wf0, wf1, wf2, wf3, wf4, wf5, wf6, wf7, wf8;
    {
        const unsigned short* wb = &Wfrag[((size_t)((kt0 * 2 + dt) * 64 + lane)) << 3];
        wf0 = *(const f16x8*)(wb + 0 * 1024);
        wf1 = *(const f16x8*)(wb + 1 * 1024);
        wf2 = *(const f16x8*)(wb + 2 * 1024);
        wf3 = *(const f16x8*)(wb + 3 * 1024);
        wf4 = *(const f16x8*)(wb + 4 * 1024);
        wf5 = *(const f16x8*)(wb + 5 * 1024);
        wf6 = *(const f16x8*)(wb + 6 * 1024);
        wf7 = *(const f16x8*)(wb + 7 * 1024);
        wf8 = *(const f16x8*)(wb + 8 * 1024);
    }

    // basis^T read rows per nt: phys(k') = k'<18 ? 2k' : (k'<36 ? 2k'-35 : 36)
    const int ph0 = 2 * l15;
    const int ph1 = (l15 < 2) ? (32 + 2 * l15) : (2 * l15 - 3);
    const int ph2 = (l15 < 4) ? (29 + 2 * l15) : 36;
    const int offB0 = ph0 * BAS_STRIDE + (q << 3);
    const int offB1 = ph1 * BAS_STRIDE + (q << 3);
    const int offB2 = ph2 * BAS_STRIDE + (q << 3);

    const int pA = w << 1, pB = pA | 1;

    // tile-t global loads (both points of this wave)
#define LOADTILE(T, oidxA, oidxB, omskA, omskB, ocA, ocB, onA, onB) do {      \
        const int _gpA = (n_ << 13) + (((pos << 2) | (T)) << 4) + pA;         \
        const int _gpB = _gpA + 1;                                            \
        oidxA = neigh[(_gpA << 5) | a_];                                      \
        oidxB = neigh[(_gpB << 5) | a_];                                      \
        omskA = rmask[(_gpA << 5) | a_];                                      \
        omskB = rmask[(_gpB << 5) | a_];                                      \
        ocA = *(const f32x4*)(coords4 + ((size_t)_gpA << 2));                 \
        ocB = *(const f32x4*)(coords4 + ((size_t)_gpB << 2));                 \
        onA = *(const f32x4*)(coords4 + ((size_t)(nbase_pt + oidxA) << 2));   \
        onB = *(const f32x4*)(coords4 + ((size_t)(nbase_pt + oidxB) << 2));   \
    } while (0)

    // ================= prologue: tile 0 loads + gathers =================
    int   idxA, idxB;
    float mskA, mskB;
    f32x4 cA4, cB4, nA4, nB4;
    LOADTILE(0, idxA, idxB, mskA, mskB, cA4, cB4, nA4, nB4);
    u32 gA[8], gB[8];
    gather16(inp_n, q, l15, idxA, idxB, gA, gB);

    const f32x4 z4 = {0.0f, 0.0f, 0.0f, 0.0f};

    #pragma unroll
    for (int t = 0; t < 4; ++t) {
        const int b0t = ((pos << 2) | t) << 4;

        // ---------------- geometry ----------------
        float YA[9], YB[9], rbA_A, rbB_A, rbA_B, rbB_B;
        geom(nA4[0] - cA4[0], nA4[1] - cA4[1], nA4[2] - cA4[2], mskA, h_, YA, rbA_A, rbB_A);
        geom(nB4[0] - cB4[0], nB4[1] - cB4[1], nB4[2] - cB4[2], mskB, h_, YB, rbA_B, rbB_B);

        // bas-A writes: k = 18h + tt, phys row = 2tt + h
        #pragma unroll
        for (int tt = 0; tt < 18; ++tt) {
            const float v = (tt < 9) ? rbA_A * YA[tt] : rbB_A * YA[tt - 9];
            basw[(2 * tt + h_) * BAS_STRIDE + a_] = f16bits(v);
        }

        f16x4 blo, bhi;
        blo = *(const f16x4*)&basw[offB0]; bhi = *(const f16x4*)&basw[offB0 + 4];
        const f16x8 BfA0 = __builtin_shufflevector(blo, bhi, 0, 1, 2, 3, 4, 5, 6, 7);
        blo = *(const f16x4*)&basw[offB1]; bhi = *(const f16x4*)&basw[offB1 + 4];
        const f16x8 BfA1 = __builtin_shufflevector(blo, bhi, 0, 1, 2, 3, 4, 5, 6, 7);
        blo = *(const f16x4*)&basw[offB2]; bhi = *(const f16x4*)&basw[offB2 + 4];
        const f16x8 BfA2 = __builtin_shufflevector(blo, bhi, 0, 1, 2, 3, 4, 5, 6, 7);

        union { f16x8 v; u32 u[4]; } afA0, afA1, afB0, afB1;
        #pragma unroll
        for (int j4 = 0; j4 < 4; ++j4) {
            afA0.u[j4] = __builtin_amdgcn_perm(gA[2 * j4 + 1], gA[2 * j4], 0x05040100u);
            afA1.u[j4] = __builtin_amdgcn_perm(gA[2 * j4 + 1], gA[2 * j4], 0x07060302u);
        }
        f32x4 DA00 = __builtin_amdgcn_mfma_f32_16x16x32_f16(afA0.v, BfA0, z4, 0, 0, 0);
        f32x4 DA01 = __builtin_amdgcn_mfma_f32_16x16x32_f16(afA0.v, BfA1, z4, 0, 0, 0);
        f32x4 DA02 = __builtin_amdgcn_mfma_f32_16x16x32_f16(afA0.v, BfA2, z4, 0, 0, 0);
        f32x4 DA10 = __builtin_amdgcn_mfma_f32_16x16x32_f16(afA1.v, BfA0, z4, 0, 0, 0);
        f32x4 DA11 = __builtin_amdgcn_mfma_f32_16x16x32_f16(afA1.v, BfA1, z4, 0, 0, 0);
        f32x4 DA12 = __builtin_amdgcn_mfma_f32_16x16x32_f16(afA1.v, BfA2, z4, 0, 0, 0);

        // bas-B writes (after Bf-A reads in same-wave DS order)
        #pragma unroll
        for (int tt = 0; tt < 18; ++tt) {
            const float v = (tt < 9) ? rbA_B * YB[tt] : rbB_B * YB[tt - 9];
            basw[(2 * tt + h_) * BAS_STRIDE + a_] = f16bits(v);
        }
        blo = *(const f16x4*)&basw[offB0]; bhi = *(const f16x4*)&basw[offB0 + 4];
        const f16x8 BfB0 = __builtin_shufflevector(blo, bhi, 0, 1, 2, 3, 4, 5, 6, 7);
        blo = *(const f16x4*)&basw[offB1]; bhi = *(const f16x4*)&basw[offB1 + 4];
        const f16x8 BfB1 = __builtin_shufflevector(blo, bhi, 0, 1, 2, 3, 4, 5, 6, 7);
        blo = *(const f16x4*)&basw[offB2]; bhi = *(const f16x4*)&basw[offB2 + 4];
        const f16x8 BfB2 = __builtin_shufflevector(blo, bhi, 0, 1, 2, 3, 4, 5, 6, 7);

        #pragma unroll
        for (int j4 = 0; j4 < 4; ++j4) {
            afB0.u[j4] = __builtin_amdgcn_perm(gB[2 * j4 + 1], gB[2 * j4], 0x05040100u);
            afB1.u[j4] = __builtin_amdgcn_perm(gB[2 * j4 + 1], gB[2 * j4], 0x07060302u);
        }
        f32x4 DB00 = __builtin_amdgcn_mfma_f32_16x16x32_f16(afB0.v, BfB0, z4, 0, 0, 0);
        f32x4 DB01 = __builtin_amdgcn_mfma_f32_16x16x32_f16(afB0.v, BfB1, z4, 0, 0, 0);
        f32x4 DB02 = __builtin_amdgcn_mfma_f32_16x16x32_f16(afB0.v, BfB2, z4, 0, 0, 0);
        f32x4 DB10 = __builtin_amdgcn_mfma_f32_16x16x32_f16(afB1.v, BfB0, z4, 0, 0, 0);
        f32x4 DB11 = __builtin_amdgcn_mfma_f32_16x16x32_f16(afB1.v, BfB1, z4, 0, 0, 0);
        f32x4 DB12 = __builtin_amdgcn_mfma_f32_16x16x32_f16(afB1.v, BfB2, z4, 0, 0, 0);

        // ---- prefetch next tile's loads (hide under Mb writes + phase 2) ----
        int   nidxA = 0, nidxB = 0;
        float nmskA = 0.f, nmskB = 0.f;
        f32x4 ncA4 = z4, ncB4 = z4, nnA4 = z4, nnB4 = z4;
        if (t < 3) {
            LOADTILE(t + 1, nidxA, nidxB, nmskA, nmskB, ncA4, ncB4, nnA4, nnB4);
        }

        // ---- D -> Mb[k'][p][c] ----
        {
            const int rowpA = pA * 36 + (q << 2);
            const int a0 = l15 * 580 + rowpA;          // nt=0
            const int a1 = (16 + l15) * 580 + rowpA;   // nt=1
            *(u32*)&Mb_s[a0]      = pk16(DA00[0], DA00[1]);
            *(u32*)&Mb_s[a0 + 2]  = pk16(DA00[2], DA00[3]);
            *(u32*)&Mb_s[a0 + 16] = pk16(DA10[0], DA10[1]);
            *(u32*)&Mb_s[a0 + 18] = pk16(DA10[2], DA10[3]);
            *(u32*)&Mb_s[a1]      = pk16(DA01[0], DA01[1]);
            *(u32*)&Mb_s[a1 + 2]  = pk16(DA01[2], DA01[3]);
            *(u32*)&Mb_s[a1 + 16] = pk16(DA11[0], DA11[1]);
            *(u32*)&Mb_s[a1 + 18] = pk16(DA11[2], DA11[3]);
            const int rowpB = pB * 36 + (q << 2);
            const int c0 = l15 * 580 + rowpB;
            const int c1 = (16 + l15) * 580 + rowpB;
            *(u32*)&Mb_s[c0]      = pk16(DB00[0], DB00[1]);
            *(u32*)&Mb_s[c0 + 2]  = pk16(DB00[2], DB00[3]);
            *(u32*)&Mb_s[c0 + 16] = pk16(DB10[0], DB10[1]);
            *(u32*)&Mb_s[c0 + 18] = pk16(DB10[2], DB10[3]);
            *(u32*)&Mb_s[c1]      = pk16(DB01[0], DB01[1]);
            *(u32*)&Mb_s[c1 + 2]  = pk16(DB01[2], DB01[3]);
            *(u32*)&Mb_s[c1 + 16] = pk16(DB11[0], DB11[1]);
            *(u32*)&Mb_s[c1 + 18] = pk16(DB11[2], DB11[3]);
            if (l15 < 4) {   // nt=2: k' = 32..35
                const int a2 = (32 + l15) * 580 + rowpA;
                *(u32*)&Mb_s[a2]      = pk16(DA02[0], DA02[1]);
                *(u32*)&Mb_s[a2 + 2]  = pk16(DA02[2], DA02[3]);
                *(u32*)&Mb_s[a2 + 16] = pk16(DA12[0], DA12[1]);
                *(u32*)&Mb_s[a2 + 18] = pk16(DA12[2], DA12[3]);
                const int c2 = (32 + l15) * 580 + rowpB;
                *(u32*)&Mb_s[c2]      = pk16(DB02[0], DB02[1]);
                *(u32*)&Mb_s[c2 + 2]  = pk16(DB02[2], DB02[3]);
                *(u32*)&Mb_s[c2 + 16] = pk16(DB12[0], DB12[1]);
                *(u32*)&Mb_s[c2 + 18] = pk16(DB12[2], DB12[3]);
            }
        }
        __syncthreads();   // sync1: Mb complete

        // ---- issue next tile's feat gathers (hide under phase 2) ----
        u32 ngA[8], ngB[8];
        if (t < 3) {
            gather16(inp_n, q, l15, nidxA, nidxB, ngA, ngB);
        }

        // ---- Phase 2: pure LDS + MFMA, fully unrolled ----
        {
            f32x4 acc2 = {0.0f, 0.0f, 0.0f, 0.0f};
            #define P2_STEP(I, WF)                                                       \
            {                                                                            \
                const int mbase = (kt0 + I) * 580 + l15 * 36 + (q << 3);                 \
                const f16x4 mlo = *(const f16x4*)&Mb_s[mbase];                           \
                const f16x4 mhi = *(const f16x4*)&Mb_s[mbase + 4];                       \
                const f16x8 bf  = __builtin_shufflevector(mlo, mhi, 0,1,2,3,4,5,6,7);    \
                acc2 = __builtin_amdgcn_mfma_f32_16x16x32_f16(WF, bf, acc2, 0, 0, 0);    \
            }
            P2_STEP(0, wf0) P2_STEP(1, wf1) P2_STEP(2, wf2)
            P2_STEP(3, wf3) P2_STEP(4, wf4) P2_STEP(5, wf5)
            P2_STEP(6, wf6) P2_STEP(7, wf7) P2_STEP(8, wf8)
            #undef P2_STEP
            *(f32x4*)&Cp[(w * 64 + lane) * 4] = acc2;
        }
        __syncthreads();   // sync2: Cp complete (also fences Mb reads for next tile)

        if (w < 2) {
            const int dt2 = w;
            f32x4 s = *(const f32x4*)&Cp[((dt2 * 4 + 0) * 64 + lane) * 4];
            #pragma unroll
            for (int rphase = 1; rphase < 4; ++rphase) {
                const f32x4 tt = *(const f32x4*)&Cp[((dt2 * 4 + rphase) * 64 + lane) * 4];
                s[0] += tt[0]; s[1] += tt[1]; s[2] += tt[2]; s[3] += tt[3];
            }
            const int drow = dt2 * 16 + (lane >> 4) * 4;
            const int col  = b0t + (lane & 15);
            #pragma unroll
            for (int rr = 0; rr < 4; ++rr) {
                out[(((n_ << 5) + drow + rr) << 13) + col] = s[rr];
            }
        }
        // Cp hazard across tiles: next Cp write happens after next sync1, which
        // waves 0/1 only reach after finishing this reduce -> safe.

        // ---- rotate pipeline regs ----
        if (t < 3) {
            idxA = nidxA; idxB = nidxB; mskA = nmskA; mskB = nmskB;
            cA4 = ncA4; cB4 = ncB4; nA4 = nnA4; nB4 = nnB4;
            #pragma unroll
            for (int j = 0; j < 8; ++j) { gA[j] = ngA[j]; gB[j] = ngB[j]; }
        }
    }
#undef LOADTILE
}

extern "C" void kernel_launch(void* const* d_in, const int* in_sizes, int n_in,
                              void* d_out, int out_size, void* d_ws, size_t ws_size,
                              hipStream_t stream)
{
    const float* inp    = (const float*)d_in[0];
    const float* coords = (const float*)d_in[1];
    const float* rmask  = (const float*)d_in[2];
    const float* W      = (const float*)d_in[3];
    const int*   neigh  = (const int*)d_in[4];
    float*       outp   = (float*)d_out;

    unsigned short* inp_t16 = (unsigned short*)d_ws;                        // 2 MB f16 (interleaved)
    unsigned short* Wfrag   = (unsigned short*)((char*)d_ws + (2u << 20));  // 73.7 KB
    float*          coords4 = (float*)((char*)d_ws + (4u << 20));           // 512 KB float4

    prep_kernel<<<1296, 256, 0, stream>>>(inp, W, coords, inp_t16, Wfrag, coords4);
    se3_main<<<512, 512, 0, stream>>>(inp_t16, coords4, rmask, neigh, Wfrag, outp);
}

// Round 4
// 90.108 us; speedup vs baseline: 1.0316x; 1.0316x over previous
//
#include <hip/hip_runtime.h>
#include <hip/hip_bf16.h>

// Problem constants (fixed): n=4, b=8192, a=32, c_in=32, d_out=32,
// n_basis=36 (4 radii x 9 SH), ck=1152.
// inputs: [0] input (4,32,8192) f32, [1] coords (4,8192,3) f32,
//         [2] relative_mask (4,8192,32) f32, [3] W (32,32,36) f32,
//         [4] neighbors (4,8192,32) i32
// output: (4,32,8192) f32
//
// R14 = R12 structure (R13 persistent pipeline REVERTED: +4.3us regression,
// likely VGPR pressure + serialized prefetch chain) + DS-instruction diet:
//  (a) bas rr-pair packing: writer packs (rb_even*Y[s], rb_odd*Y[s]) into one
//      u32 -> 9 ds_write_b32/pass (was 18 ds_write_b16). Layout
//      bas[row=(rr>>1)*9+s][a][par=rr&1], row stride 72 u16 (144B, 16B-aligned
//      rows). Reader: 2 ds_read_b128 + 4 v_perm per Bf; parity partners are
//      same-address -> LDS broadcast.
//  (b) Mb writes b32 pairs -> b64 (addresses were already consecutive and
//      8B-aligned): 24 -> 12 DS instr.
//  (c) idxs packed u32 (idxA | idxB<<16): 1 write + 8 reads serve both
//      passes: 18 -> 9 DS instr.
// DS total ~110 -> ~70 instr/wave-tile. Everything else identical to R12
// (16 pts/block, 512 thr, 2 passes/wave, f16 inp_t interleaved, coords4,
// rsqrt geom, fully-unrolled phase 2, grid 2048).

typedef _Float16 f16x8 __attribute__((ext_vector_type(8)));
typedef _Float16 f16x4 __attribute__((ext_vector_type(4)));
typedef __fp16   h16x2 __attribute__((ext_vector_type(2)));
typedef float    f32x4 __attribute__((ext_vector_type(4)));
typedef unsigned int u32;
typedef unsigned long long u64;
typedef u32 u32x4 __attribute__((ext_vector_type(4)));

__device__ __forceinline__ u32 pk16(float a, float b) {      // RTZ pack (Mb path, as before)
    union { h16x2 v; u32 u; } cv;
    cv.v = __builtin_amdgcn_cvt_pkrtz(a, b);
    return cv.u;
}
__device__ __forceinline__ u32 pkrte(float a, float b) {     // RTE pack (bas path: keeps R12 rounding)
    union { _Float16 h[2]; u32 u; } cv;
    cv.h[0] = (_Float16)a; cv.h[1] = (_Float16)b;
    return cv.u;
}
__device__ __forceinline__ unsigned short f16bits(float v) {
    const _Float16 hv = (_Float16)v;
    return __builtin_bit_cast(unsigned short, hv);
}
__device__ __forceinline__ u64 mk64(u32 lo, u32 hi) {
    return (u64)lo | ((u64)hi << 32);
}

#define BAS_ROWS 19      // 18 data rows + 1 dummy (read-only pad for nt2 l15>=4)
#define BAS_STRIDE 72    // u16 per row (144B: 16B-aligned rows for b128 reads)

// geometry: SH l=0..2 and the h-half radial pair (mask folded in)
__device__ __forceinline__ void geom(float dx, float dy, float dz, float msk, int h_,
                                     float Y[9], float& rbA, float& rbB) {
    const float d2  = dx * dx + dy * dy + dz * dz;
    const float inv = rsqrtf(d2 + 1e-16f);   // == 1/(r+1e-8) within f16 eps; exact at d2=0
    const float r   = d2 * inv;
    const float x = dx * inv, y = dy * inv, z = dz * inv;
    Y[0] = 0.28209479f;
    Y[1] = 0.48860251f * x;
    Y[2] = 0.48860251f * y;
    Y[3] = 0.48860251f * z;
    Y[4] = 1.09254843f * x * y;
    Y[5] = 1.09254843f * y * z;
    Y[6] = 0.31539157f * (3.0f * z * z - 1.0f);
    Y[7] = 1.09254843f * x * z;
    Y[8] = 0.54627421f * (x * x - y * y);
    const float sA = r - (h_ ? 1.5f : 0.5f);   // rr = 2h
    const float sB = r - (h_ ? 2.0f : 1.0f);   // rr = 2h+1
    rbA = __expf(sA * sA * -4.0f) * msk;
    rbB = __expf(sB * sB * -4.0f) * msk;
}

// reader: 8 a-consecutive basis values of one (row,par) as f16x8
__device__ __forceinline__ f16x8 bfread(const unsigned short* __restrict__ basw,
                                        int off_u16, u32 sel) {
    const u32x4 R0 = *(const u32x4*)&basw[off_u16];
    const u32x4 R1 = *(const u32x4*)&basw[off_u16 + 8];
    union { f16x8 v; u32 u[4]; } o;
    o.u[0] = __builtin_amdgcn_perm(R0[1], R0[0], sel);
    o.u[1] = __builtin_amdgcn_perm(R0[3], R0[2], sel);
    o.u[2] = __builtin_amdgcn_perm(R1[1], R1[0], sel);
    o.u[3] = __builtin_amdgcn_perm(R1[3], R1[2], sel);
    return o.v;
}

// ---------------- prep: LDS-tiled transpose (f32 -> f16, c-interleaved) + W frags
// inp_t16 row layout (32 u16 per point): pos = 2*(c&15) + (c>>4), i.e.
// [c0,c16,c1,c17,...] so u32 @ 4*l15 = (lo: c=l15, hi: c=l15+16).
// Wfrag[t], t = ((kt*2+dt)*64 + l)*8 + j  holds  W[d][c*36 + k'] as f16, where
// d = dt*16 + (l&15), c = (l>>4)*8+j, k' = kt.
// coords4[p] = float4(x,y,z,0) for point p (one dwordx4 gather in main).
__global__ __launch_bounds__(256) void prep_kernel(
    const float* __restrict__ inp, const float* __restrict__ W,
    const float* __restrict__ coords,
    unsigned short* __restrict__ inp_t16, unsigned short* __restrict__ Wfrag,
    float* __restrict__ coords4)
{
    if (blockIdx.x < 1024) {
        __shared__ float T[32][33];
        const int n  = blockIdx.x >> 8;
        const int b0 = (blockIdx.x & 255) << 5;
        const int bx = threadIdx.x & 31;
        const int cy = threadIdx.x >> 5;   // 0..7
        #pragma unroll
        for (int r = 0; r < 4; ++r) {
            const int cc = cy + r * 8;
            T[bx][cc] = inp[((n << 5) + cc) * 8192 + b0 + bx];
        }
        __syncthreads();
        const int cpos = ((bx & 15) << 1) | (bx >> 4);   // interleaved column
        #pragma unroll
        for (int r = 0; r < 4; ++r) {
            const int by = cy + r * 8;
            inp_t16[((n << 13) + b0 + by) * 32 + cpos] = f16bits(T[by][bx]);
        }
    } else if (blockIdx.x < 1168) {
        const int t = (blockIdx.x - 1024) * 256 + threadIdx.x;   // 0..36863
        if (t < 36 * 2 * 64 * 8) {
            const int j  = t & 7;
            const int l  = (t >> 3) & 63;
            const int dt = (t >> 9) & 1;
            const int kt = t >> 10;                  // k' = 0..35
            const int d  = dt * 16 + (l & 15);
            const int c  = ((l >> 4) << 3) + j;
            Wfrag[t] = f16bits(W[d * 1152 + c * 36 + kt]);
        }
    } else {
        const int t = (blockIdx.x - 1168) * 256 + threadIdx.x;   // 0..32767
        f32x4 v;
        v[0] = coords[3 * t + 0];
        v[1] = coords[3 * t + 1];
        v[2] = coords[3 * t + 2];
        v[3] = 0.0f;
        *(f32x4*)(coords4 + ((size_t)t << 2)) = v;
    }
}

// ---------------- main fused kernel: 512 threads, 16 points/block, 2 passes/wave ----------
__global__ __launch_bounds__(512, 4) void se3_main(
    const unsigned short* __restrict__ inp_t16, const float* __restrict__ coords4,
    const float* __restrict__ rmask, const int* __restrict__ neigh,
    const unsigned short* __restrict__ Wfrag, float* __restrict__ out)
{
    // Mb[k'=0..35][p=0..15][c=0..31] f16; p-row 72B, plane 1160B (580 u16, 8B pad).
    __shared__ __align__(16) unsigned short Mb_s[36 * 580];                // 41,760 B
    // basis per wave: [row=(rr>>1)*9+s][a][par], 19 rows x 72 u16.
    __shared__ __align__(16) unsigned short bas[8][BAS_ROWS * BAS_STRIDE]; // 21,888 B
    __shared__ u32 idxs2[8][32];                                           //  1,024 B
    __shared__ __align__(16) float Cp[8 * 64 * 4];                         //  8,192 B
    // total 72,864 B -> 2 blocks/CU = 16 waves/CU

    const int tid  = threadIdx.x;
    const int lane = tid & 63;
    const int w    = tid >> 6;      // wave 0..7
    const int l15  = lane & 15;
    const int q    = lane >> 4;     // 0..3
    const int a_   = lane & 31;
    const int h_   = lane >> 5;

    // XCD-aware swizzle: XCD pair {2n,2n+1} serves batch n
    const int blk = blockIdx.x;
    const int n_  = (blk & 7) >> 1;
    const int pos = ((blk >> 3) << 1) | (blk & 1);
    const int b0  = pos << 4;
    const int gp0 = (n_ << 13) | b0;
    const int nbase_pt = n_ << 13;
    const unsigned short* __restrict__ inp_n = inp_t16 + ((size_t)n_ << 18);

    unsigned short* basw = &bas[w][0];

    // ---- hoist this wave's 9 phase-2 W-fragments into VGPRs (overlaps phase 1) ----
    const int dt  = w >> 2;       // 0,1
    const int seg = w & 3;        // 9 kt-steps each
    const int kt0 = seg * 9;
    f16x8 wf0, wf1, wf2, wf3, wf4, wf5, wf6, wf7, wf8;
    {
        const unsigned short* wb = &Wfrag[((size_t)((kt0 * 2 + dt) * 64 + lane)) << 3];
        wf0 = *(const f16x8*)(wb + 0 * 1024);
        wf1 = *(const f16x8*)(wb + 1 * 1024);
        wf2 = *(const f16x8*)(wb + 2 * 1024);
        wf3 = *(const f16x8*)(wb + 3 * 1024);
        wf4 = *(const f16x8*)(wb + 4 * 1024);
        wf5 = *(const f16x8*)(wb + 5 * 1024);
        wf6 = *(const f16x8*)(wb + 6 * 1024);
        wf7 = *(const f16x8*)(wb + 7 * 1024);
        wf8 = *(const f16x8*)(wb + 8 * 1024);
    }

    // ---- basis read addressing: col l15 of nt-pass holds k' = nt*16+l15 ----
    // k' -> rr = k'/9, s = k'%9, row = (rr>>1)*9+s, par = rr&1
    int offB0, offB1, offB2;
    u32 sel0, sel1, sel2;
    {
        #define KSPLIT(K, OFF, SEL) {                                      \
            const int rr = ((K) * 29) >> 8;                                \
            const int s  = (K) - rr * 9;                                   \
            const int row = ((rr >> 1) * 9) + s;                           \
            OFF = row * BAS_STRIDE + (q << 4);                             \
            SEL = (rr & 1) ? 0x07060302u : 0x05040100u;                    \
        }
        KSPLIT(l15, offB0, sel0);
        KSPLIT(16 + l15, offB1, sel1);
        const int k2 = (l15 < 4) ? (32 + l15) : 0;
        KSPLIT(k2, offB2, sel2);
        if (l15 >= 4) { offB2 = 18 * BAS_STRIDE + (q << 4); sel2 = 0x05040100u; }  // dummy row
        #undef KSPLIT
    }

    const int pA = w << 1, pB = pA | 1;
    const int gpA = gp0 + pA, gpB = gp0 + pB;

    // ================= hoisted global loads (both passes) =================
    const int   idxA = neigh[(gpA << 5) | a_];
    const int   idxB = neigh[(gpB << 5) | a_];
    const float mskA = rmask[(gpA << 5) | a_];
    const float mskB = rmask[(gpB << 5) | a_];
    const f32x4 cA4 = *(const f32x4*)(coords4 + ((size_t)gpA << 2));
    const f32x4 cB4 = *(const f32x4*)(coords4 + ((size_t)gpB << 2));
    if (lane < 32) {
        idxs2[w][a_] = (u32)(unsigned short)idxA | ((u32)idxB << 16);
    }
    const f32x4 nA4 = *(const f32x4*)(coords4 + ((size_t)(nbase_pt + idxA) << 2));
    const f32x4 nB4 = *(const f32x4*)(coords4 + ((size_t)(nbase_pt + idxB) << 2));
    const float dxA = nA4[0] - cA4[0], dyA = nA4[1] - cA4[1], dzA = nA4[2] - cA4[2];
    const float dxB = nB4[0] - cB4[0], dyB = nB4[1] - cB4[1], dzB = nB4[2] - cB4[2];

    // packed idx reads: one u32 serves both passes
    u32 rid[8];
    #pragma unroll
    for (int j = 0; j < 8; ++j) rid[j] = idxs2[w][(q << 3) + j];

    // feat gathers for both passes: ONE u32 per (pass, j) covers (c=l15, c=l15+16)
    u32 gA[8], gB[8];
    #pragma unroll
    for (int j = 0; j < 8; ++j) {
        gA[j] = *(const u32*)(inp_n + ((rid[j] & 0xffffu) << 5) + (l15 << 1));
    }
    #pragma unroll
    for (int j = 0; j < 8; ++j) {
        gB[j] = *(const u32*)(inp_n + ((rid[j] >> 16) << 5) + (l15 << 1));
    }

    // ================= geometry (VALU, overlaps the gathers) =================
    float YA[9], YB[9], rbA_A, rbB_A, rbA_B, rbB_B;
    geom(dxA, dyA, dzA, mskA, h_, YA, rbA_A, rbB_A);
    geom(dxB, dyB, dzB, mskB, h_, YB, rbA_B, rbB_B);

    // bas-A writes: 9 packed b32 per lane: row = h*9+s, u32 = (rr even, rr odd)
    #pragma unroll
    for (int s = 0; s < 9; ++s) {
        *(u32*)&basw[(h_ * 9 + s) * BAS_STRIDE + (a_ << 1)] = pkrte(rbA_A * YA[s], rbB_A * YA[s]);
    }

    // Bf-A reads (before bas-B writes; same-wave DS order)
    const f16x8 BfA0 = bfread(basw, offB0, sel0);
    const f16x8 BfA1 = bfread(basw, offB1, sel1);
    const f16x8 BfA2 = bfread(basw, offB2, sel2);

    // assemble A-fragments: v_perm_b32 splits the interleaved u32 pairs
    union { f16x8 v; u32 u[4]; } afA0, afA1, afB0, afB1;
    #pragma unroll
    for (int j4 = 0; j4 < 4; ++j4) {
        afA0.u[j4] = __builtin_amdgcn_perm(gA[2 * j4 + 1], gA[2 * j4], 0x05040100u);
        afA1.u[j4] = __builtin_amdgcn_perm(gA[2 * j4 + 1], gA[2 * j4], 0x07060302u);
    }
    const f32x4 z4 = {0.0f, 0.0f, 0.0f, 0.0f};
    f32x4 DA00 = __builtin_amdgcn_mfma_f32_16x16x32_f16(afA0.v, BfA0, z4, 0, 0, 0);
    f32x4 DA01 = __builtin_amdgcn_mfma_f32_16x16x32_f16(afA0.v, BfA1, z4, 0, 0, 0);
    f32x4 DA02 = __builtin_amdgcn_mfma_f32_16x16x32_f16(afA0.v, BfA2, z4, 0, 0, 0);
    f32x4 DA10 = __builtin_amdgcn_mfma_f32_16x16x32_f16(afA1.v, BfA0, z4, 0, 0, 0);
    f32x4 DA11 = __builtin_amdgcn_mfma_f32_16x16x32_f16(afA1.v, BfA1, z4, 0, 0, 0);
    f32x4 DA12 = __builtin_amdgcn_mfma_f32_16x16x32_f16(afA1.v, BfA2, z4, 0, 0, 0);

    // bas-B writes (after Bf-A reads in program order)
    #pragma unroll
    for (int s = 0; s < 9; ++s) {
        *(u32*)&basw[(h_ * 9 + s) * BAS_STRIDE + (a_ << 1)] = pkrte(rbA_B * YB[s], rbB_B * YB[s]);
    }
    const f16x8 BfB0 = bfread(basw, offB0, sel0);
    const f16x8 BfB1 = bfread(basw, offB1, sel1);
    const f16x8 BfB2 = bfread(basw, offB2, sel2);

    #pragma unroll
    for (int j4 = 0; j4 < 4; ++j4) {
        afB0.u[j4] = __builtin_amdgcn_perm(gB[2 * j4 + 1], gB[2 * j4], 0x05040100u);
        afB1.u[j4] = __builtin_amdgcn_perm(gB[2 * j4 + 1], gB[2 * j4], 0x07060302u);
    }
    f32x4 DB00 = __builtin_amdgcn_mfma_f32_16x16x32_f16(afB0.v, BfB0, z4, 0, 0, 0);
    f32x4 DB01 = __builtin_amdgcn_mfma_f32_16x16x32_f16(afB0.v, BfB1, z4, 0, 0, 0);
    f32x4 DB02 = __builtin_amdgcn_mfma_f32_16x16x32_f16(afB0.v, BfB2, z4, 0, 0, 0);
    f32x4 DB10 = __builtin_amdgcn_mfma_f32_16x16x32_f16(afB1.v, BfB0, z4, 0, 0, 0);
    f32x4 DB11 = __builtin_amdgcn_mfma_f32_16x16x32_f16(afB1.v, BfB1, z4, 0, 0, 0);
    f32x4 DB12 = __builtin_amdgcn_mfma_f32_16x16x32_f16(afB1.v, BfB2, z4, 0, 0, 0);

    // ---- D -> Mb[k'][p][c]: consecutive-c u32 pairs -> b64 writes ----
    {
        const int rowpA = pA * 36 + (q << 2);
        const int a0 = l15 * 580 + rowpA;          // nt=0
        const int a1 = (16 + l15) * 580 + rowpA;   // nt=1
        *(u64*)&Mb_s[a0]      = mk64(pk16(DA00[0], DA00[1]), pk16(DA00[2], DA00[3]));
        *(u64*)&Mb_s[a0 + 16] = mk64(pk16(DA10[0], DA10[1]), pk16(DA10[2], DA10[3]));
        *(u64*)&Mb_s[a1]      = mk64(pk16(DA01[0], DA01[1]), pk16(DA01[2], DA01[3]));
        *(u64*)&Mb_s[a1 + 16] = mk64(pk16(DA11[0], DA11[1]), pk16(DA11[2], DA11[3]));
        const int rowpB = pB * 36 + (q << 2);
        const int c0 = l15 * 580 + rowpB;
        const int c1 = (16 + l15) * 580 + rowpB;
        *(u64*)&Mb_s[c0]      = mk64(pk16(DB00[0], DB00[1]), pk16(DB00[2], DB00[3]));
        *(u64*)&Mb_s[c0 + 16] = mk64(pk16(DB10[0], DB10[1]), pk16(DB10[2], DB10[3]));
        *(u64*)&Mb_s[c1]      = mk64(pk16(DB01[0], DB01[1]), pk16(DB01[2], DB01[3]));
        *(u64*)&Mb_s[c1 + 16] = mk64(pk16(DB11[0], DB11[1]), pk16(DB11[2], DB11[3]));
        if (l15 < 4) {   // nt=2: k' = 32..35
            const int a2 = (32 + l15) * 580 + rowpA;
            *(u64*)&Mb_s[a2]      = mk64(pk16(DA02[0], DA02[1]), pk16(DA02[2], DA02[3]));
            *(u64*)&Mb_s[a2 + 16] = mk64(pk16(DA12[0], DA12[1]), pk16(DA12[2], DA12[3]));
            const int c2 = (32 + l15) * 580 + rowpB;
            *(u64*)&Mb_s[c2]      = mk64(pk16(DB02[0], DB02[1]), pk16(DB02[2], DB02[3]));
            *(u64*)&Mb_s[c2 + 16] = mk64(pk16(DB12[0], DB12[1]), pk16(DB12[2], DB12[3]));
        }
    }
    __syncthreads();

    // ============ Phase 2: pure LDS + MFMA, fully unrolled (wf stays in VGPRs) ============
    {
        f32x4 acc2 = {0.0f, 0.0f, 0.0f, 0.0f};
        #define P2_STEP(I, WF)                                                       \
        {                                                                            \
            const int mbase = (kt0 + I) * 580 + l15 * 36 + (q << 3);                 \
            const f16x4 mlo = *(const f16x4*)&Mb_s[mbase];                           \
            const f16x4 mhi = *(const f16x4*)&Mb_s[mbase + 4];                       \
            const f16x8 bf  = __builtin_shufflevector(mlo, mhi, 0,1,2,3,4,5,6,7);    \
            acc2 = __builtin_amdgcn_mfma_f32_16x16x32_f16(WF, bf, acc2, 0, 0, 0);    \
        }
        P2_STEP(0, wf0) P2_STEP(1, wf1) P2_STEP(2, wf2)
        P2_STEP(3, wf3) P2_STEP(4, wf4) P2_STEP(5, wf5)
        P2_STEP(6, wf6) P2_STEP(7, wf7) P2_STEP(8, wf8)
        #undef P2_STEP
        *(f32x4*)&Cp[(w * 64 + lane) * 4] = acc2;   // dedicated buffer
    }
    __syncthreads();

    if (w < 2) {
        const int dt2 = w;
        f32x4 s = *(const f32x4*)&Cp[((dt2 * 4 + 0) * 64 + lane) * 4];
        #pragma unroll
        for (int rphase = 1; rphase < 4; ++rphase) {
            const f32x4 t = *(const f32x4*)&Cp[((dt2 * 4 + rphase) * 64 + lane) * 4];
            s[0] += t[0]; s[1] += t[1]; s[2] += t[2]; s[3] += t[3];
        }
        const int drow = dt2 * 16 + (lane >> 4) * 4;   // D row = (lane>>4)*4 + reg
        const int col  = b0 + (lane & 15);
        #pragma unroll
        for (int rr = 0; rr < 4; ++rr) {
            out[(((n_ << 5) + drow + rr) << 13) + col] = s[rr];
        }
    }
}

extern "C" void kernel_launch(void* const* d_in, const int* in_sizes, int n_in,
                              void* d_out, int out_size, void* d_ws, size_t ws_size,
                              hipStream_t stream)
{
    const float* inp    = (const float*)d_in[0];
    const float* coords = (const float*)d_in[1];
    const float* rmask  = (const float*)d_in[2];
    const float* W      = (const float*)d_in[3];
    const int*   neigh  = (const int*)d_in[4];
    float*       outp   = (float*)d_out;

    unsigned short* inp_t16 = (unsigned short*)d_ws;                        // 2 MB f16 (interleaved)
    unsigned short* Wfrag   = (unsigned short*)((char*)d_ws + (2u << 20));  // 73.7 KB
    float*          coords4 = (float*)((char*)d_ws + (4u << 20));           // 512 KB float4

    prep_kernel<<<1296, 256, 0, stream>>>(inp, W, coords, inp_t16, Wfrag, coords4);
    se3_main<<<2048, 512, 0, stream>>>(inp_t16, coords4, rmask, neigh, Wfrag, outp);
}

// Round 6
// 88.645 us; speedup vs baseline: 1.0486x; 1.0165x over previous
//
#include <hip/hip_runtime.h>
#include <hip/hip_bf16.h>

// Problem constants (fixed): n=4, b=8192, a=32, c_in=32, d_out=32,
// n_basis=36 (4 radii x 9 SH), ck=1152.
// inputs: [0] input (4,32,8192) f32, [1] coords (4,8192,3) f32,
//         [2] relative_mask (4,8192,32) f32, [3] W (32,32,36) f32,
//         [4] neighbors (4,8192,32) i32
// output: (4,32,8192) f32
//
// R16 = R12 (best verified, 88.7us) + three zero-risk additions:
//  (a) s_setprio(1) around the MFMA clusters (T5): 2 independent blocks/CU
//      give the scheduler role diversity; boost MFMA-entering waves.
//  (b) phase-2 dual accumulator: splits the 9-MFMA serial acc chain into
//      5+4 independent chains (+4 VGPR, one final f32x4 add).
//  (c) 8-wave epilogue reduce (was w<2): w encodes (dt2=w>>2, rr=w&3);
//      each thread sums 4 scalars + 1 store -> ~4x shorter block tail.
// R13/R15 pipelining attempts abandoned (regression / unverifiable).

typedef _Float16 f16x8 __attribute__((ext_vector_type(8)));
typedef _Float16 f16x4 __attribute__((ext_vector_type(4)));
typedef __fp16   h16x2 __attribute__((ext_vector_type(2)));
typedef float    f32x4 __attribute__((ext_vector_type(4)));
typedef unsigned int u32;

__device__ __forceinline__ u32 pk16(float a, float b) {
    union { h16x2 v; u32 u; } cv;
    cv.v = __builtin_amdgcn_cvt_pkrtz(a, b);
    return cv.u;
}
__device__ __forceinline__ unsigned short f16bits(float v) {
    const _Float16 hv = (_Float16)v;
    return __builtin_bit_cast(unsigned short, hv);
}

#define BAS_STRIDE 44   // u16 per phys row (88B, b64-aligned, reads <=2-way)

// geometry: SH l=0..2 and the h-half radial pair (mask folded in)
__device__ __forceinline__ void geom(float dx, float dy, float dz, float msk, int h_,
                                     float Y[9], float& rbA, float& rbB) {
    const float d2  = dx * dx + dy * dy + dz * dz;
    // 1/(r+1e-8) ~= rsqrt(d2+1e-16); exact for the self-neighbor d2==0 case
    const float inv = rsqrtf(d2 + 1e-16f);
    const float r   = d2 * inv;
    const float x = dx * inv, y = dy * inv, z = dz * inv;
    Y[0] = 0.28209479f;
    Y[1] = 0.48860251f * x;
    Y[2] = 0.48860251f * y;
    Y[3] = 0.48860251f * z;
    Y[4] = 1.09254843f * x * y;
    Y[5] = 1.09254843f * y * z;
    Y[6] = 0.31539157f * (3.0f * z * z - 1.0f);
    Y[7] = 1.09254843f * x * z;
    Y[8] = 0.54627421f * (x * x - y * y);
    const float sA = r - (h_ ? 1.5f : 0.5f);
    const float sB = r - (h_ ? 2.0f : 1.0f);
    rbA = __expf(sA * sA * -4.0f) * msk;   // exp(-((r-c)/0.5)^2) = exp(-4 s^2)
    rbB = __expf(sB * sB * -4.0f) * msk;
}

// ---------------- prep: LDS-tiled transpose (f32 -> f16, c-interleaved) + W frags
// inp_t16 row layout (32 u16 per point): pos = 2*(c&15) + (c>>4), i.e.
// [c0,c16,c1,c17,...] so u32 @ 4*l15 = (lo: c=l15, hi: c=l15+16).
// Wfrag[t], t = ((kt*2+dt)*64 + l)*8 + j  holds  W[d][c*36 + k'] as f16, where
// d = dt*16 + (l&15), c = (l>>4)*8+j, k' = kt.
// coords4[p] = float4(x,y,z,0) for point p (one dwordx4 gather in main).
__global__ __launch_bounds__(256) void prep_kernel(
    const float* __restrict__ inp, const float* __restrict__ W,
    const float* __restrict__ coords,
    unsigned short* __restrict__ inp_t16, unsigned short* __restrict__ Wfrag,
    float* __restrict__ coords4)
{
    if (blockIdx.x < 1024) {
        __shared__ float T[32][33];
        const int n  = blockIdx.x >> 8;
        const int b0 = (blockIdx.x & 255) << 5;
        const int bx = threadIdx.x & 31;
        const int cy = threadIdx.x >> 5;   // 0..7
        #pragma unroll
        for (int r = 0; r < 4; ++r) {
            const int cc = cy + r * 8;
            T[bx][cc] = inp[((n << 5) + cc) * 8192 + b0 + bx];
        }
        __syncthreads();
        const int cpos = ((bx & 15) << 1) | (bx >> 4);   // interleaved column
        #pragma unroll
        for (int r = 0; r < 4; ++r) {
            const int by = cy + r * 8;
            inp_t16[((n << 13) + b0 + by) * 32 + cpos] = f16bits(T[by][bx]);
        }
    } else if (blockIdx.x < 1168) {
        const int t = (blockIdx.x - 1024) * 256 + threadIdx.x;   // 0..36863
        if (t < 36 * 2 * 64 * 8) {
            const int j  = t & 7;
            const int l  = (t >> 3) & 63;
            const int dt = (t >> 9) & 1;
            const int kt = t >> 10;                  // k' = 0..35
            const int d  = dt * 16 + (l & 15);
            const int c  = ((l >> 4) << 3) + j;
            Wfrag[t] = f16bits(W[d * 1152 + c * 36 + kt]);
        }
    } else {
        const int t = (blockIdx.x - 1168) * 256 + threadIdx.x;   // 0..32767
        f32x4 v;
        v[0] = coords[3 * t + 0];
        v[1] = coords[3 * t + 1];
        v[2] = coords[3 * t + 2];
        v[3] = 0.0f;
        *(f32x4*)(coords4 + ((size_t)t << 2)) = v;
    }
}

// ---------------- main fused kernel: 512 threads, 16 points/block, 2 passes/wave ----------
__global__ __launch_bounds__(512, 4) void se3_main(
    const unsigned short* __restrict__ inp_t16, const float* __restrict__ coords4,
    const float* __restrict__ rmask, const int* __restrict__ neigh,
    const unsigned short* __restrict__ Wfrag, float* __restrict__ out)
{
    // Mb[k'=0..35][p=0..15][c=0..31] f16; p-row 72B, plane 1160B (580 us, 8B pad).
    __shared__ __align__(16) unsigned short Mb_s[36 * 580];          // 41,760 B
    // basis^T per wave: phys = 2t + h interleave, 37 rows x 44 us.
    __shared__ __align__(16) unsigned short bas[8][37 * BAS_STRIDE]; // 26,048 B
    __shared__ unsigned short idxs[16][32];                          //  1,024 B
    __shared__ __align__(16) float Cp[8 * 64 * 4];                   //  8,192 B
    // total 77,024 B -> 2 blocks/CU = 16 waves/CU

    const int tid  = threadIdx.x;
    const int lane = tid & 63;
    const int w    = tid >> 6;      // wave 0..7
    const int l15  = lane & 15;
    const int q    = lane >> 4;     // 0..3
    const int a_   = lane & 31;
    const int h_   = lane >> 5;

    // XCD-aware swizzle: XCD pair {2n,2n+1} serves batch n
    const int blk = blockIdx.x;
    const int n_  = (blk & 7) >> 1;
    const int pos = ((blk >> 3) << 1) | (blk & 1);
    const int b0  = pos << 4;
    const int gp0 = (n_ << 13) | b0;
    const int nbase_pt = n_ << 13;
    const unsigned short* __restrict__ inp_n = inp_t16 + ((size_t)n_ << 18);

    unsigned short* basw = &bas[w][0];

    // ---- hoist this wave's 9 phase-2 W-fragments into VGPRs (overlaps phase 1) ----
    const int dt  = w >> 2;       // 0,1
    const int seg = w & 3;        // 9 kt-steps each
    const int kt0 = seg * 9;
    f16x8 wf0, wf1, wf2, wf3, wf4, wf5, wf6, wf7, wf8;
    {
        const unsigned short* wb = &Wfrag[((size_t)((kt0 * 2 + dt) * 64 + lane)) << 3];
        // consecutive kt step in Wfrag: +2*64*8 = +1024 u16
        wf0 = *(const f16x8*)(wb + 0 * 1024);
        wf1 = *(const f16x8*)(wb + 1 * 1024);
        wf2 = *(const f16x8*)(wb + 2 * 1024);
        wf3 = *(const f16x8*)(wb + 3 * 1024);
        wf4 = *(const f16x8*)(wb + 4 * 1024);
        wf5 = *(const f16x8*)(wb + 5 * 1024);
        wf6 = *(const f16x8*)(wb + 6 * 1024);
        wf7 = *(const f16x8*)(wb + 7 * 1024);
        wf8 = *(const f16x8*)(wb + 8 * 1024);
    }

    // basis^T read rows per nt: phys(k') = k'<18 ? 2k' : (k'<36 ? 2k'-35 : 36)
    const int ph0 = 2 * l15;
    const int ph1 = (l15 < 2) ? (32 + 2 * l15) : (2 * l15 - 3);
    const int ph2 = (l15 < 4) ? (29 + 2 * l15) : 36;
    const int offB0 = ph0 * BAS_STRIDE + (q << 3);
    const int offB1 = ph1 * BAS_STRIDE + (q << 3);
    const int offB2 = ph2 * BAS_STRIDE + (q << 3);

    const int pA = w << 1, pB = pA | 1;
    const int gpA = gp0 + pA, gpB = gp0 + pB;

    // ================= hoisted global loads (both passes) =================
    const int   idxA = neigh[(gpA << 5) | a_];
    const int   idxB = neigh[(gpB << 5) | a_];
    const float mskA = rmask[(gpA << 5) | a_];
    const float mskB = rmask[(gpB << 5) | a_];
    const f32x4 cA4 = *(const f32x4*)(coords4 + ((size_t)gpA << 2));
    const f32x4 cB4 = *(const f32x4*)(coords4 + ((size_t)gpB << 2));
    if (lane < 32) {
        idxs[pA][a_] = (unsigned short)idxA;
        idxs[pB][a_] = (unsigned short)idxB;
    }
    const f32x4 nA4 = *(const f32x4*)(coords4 + ((size_t)(nbase_pt + idxA) << 2));
    const f32x4 nB4 = *(const f32x4*)(coords4 + ((size_t)(nbase_pt + idxB) << 2));
    const float dxA = nA4[0] - cA4[0], dyA = nA4[1] - cA4[1], dzA = nA4[2] - cA4[2];
    const float dxB = nB4[0] - cB4[0], dyB = nB4[1] - cB4[1], dzB = nB4[2] - cB4[2];

    // feat gathers for both passes: ONE u32 per j covers (c=l15, c=l15+16)
    u32 gA[8], gB[8];
    #pragma unroll
    for (int j = 0; j < 8; ++j) {
        const int ri = idxs[pA][(q << 3) + j];
        gA[j] = *(const u32*)(inp_n + (((unsigned)ri) << 5) + (l15 << 1));
    }
    #pragma unroll
    for (int j = 0; j < 8; ++j) {
        const int ri = idxs[pB][(q << 3) + j];
        gB[j] = *(const u32*)(inp_n + (((unsigned)ri) << 5) + (l15 << 1));
    }

    // ================= geometry (VALU, overlaps the gathers) =================
    float YA[9], YB[9], rbA_A, rbB_A, rbA_B, rbB_B;
    geom(dxA, dyA, dzA, mskA, h_, YA, rbA_A, rbB_A);
    geom(dxB, dyB, dzB, mskB, h_, YB, rbA_B, rbB_B);

    // bas-A writes: k = 18h + t, phys row = 2t + h
    #pragma unroll
    for (int t = 0; t < 18; ++t) {
        const float v = (t < 9) ? rbA_A * YA[t] : rbB_A * YA[t - 9];
        basw[(2 * t + h_) * BAS_STRIDE + a_] = f16bits(v);
    }

    // Bf-A reads (b64; <=2-way banks); before bas-B writes (same-wave DS order)
    f16x4 blo, bhi;
    blo = *(const f16x4*)&basw[offB0]; bhi = *(const f16x4*)&basw[offB0 + 4];
    const f16x8 BfA0 = __builtin_shufflevector(blo, bhi, 0, 1, 2, 3, 4, 5, 6, 7);
    blo = *(const f16x4*)&basw[offB1]; bhi = *(const f16x4*)&basw[offB1 + 4];
    const f16x8 BfA1 = __builtin_shufflevector(blo, bhi, 0, 1, 2, 3, 4, 5, 6, 7);
    blo = *(const f16x4*)&basw[offB2]; bhi = *(const f16x4*)&basw[offB2 + 4];
    const f16x8 BfA2 = __builtin_shufflevector(blo, bhi, 0, 1, 2, 3, 4, 5, 6, 7);

    // assemble A-fragments: v_perm_b32 splits the interleaved u32 pairs
    union { f16x8 v; u32 u[4]; } afA0, afA1, afB0, afB1;
    #pragma unroll
    for (int j4 = 0; j4 < 4; ++j4) {
        afA0.u[j4] = __builtin_amdgcn_perm(gA[2 * j4 + 1], gA[2 * j4], 0x05040100u); // lo halves
        afA1.u[j4] = __builtin_amdgcn_perm(gA[2 * j4 + 1], gA[2 * j4], 0x07060302u); // hi halves
    }
    const f32x4 z4 = {0.0f, 0.0f, 0.0f, 0.0f};
    __builtin_amdgcn_s_setprio(1);
    f32x4 DA00 = __builtin_amdgcn_mfma_f32_16x16x32_f16(afA0.v, BfA0, z4, 0, 0, 0);
    f32x4 DA01 = __builtin_amdgcn_mfma_f32_16x16x32_f16(afA0.v, BfA1, z4, 0, 0, 0);
    f32x4 DA02 = __builtin_amdgcn_mfma_f32_16x16x32_f16(afA0.v, BfA2, z4, 0, 0, 0);
    f32x4 DA10 = __builtin_amdgcn_mfma_f32_16x16x32_f16(afA1.v, BfA0, z4, 0, 0, 0);
    f32x4 DA11 = __builtin_amdgcn_mfma_f32_16x16x32_f16(afA1.v, BfA1, z4, 0, 0, 0);
    f32x4 DA12 = __builtin_amdgcn_mfma_f32_16x16x32_f16(afA1.v, BfA2, z4, 0, 0, 0);
    __builtin_amdgcn_s_setprio(0);

    // bas-B writes (after Bf-A reads in program order)
    #pragma unroll
    for (int t = 0; t < 18; ++t) {
        const float v = (t < 9) ? rbA_B * YB[t] : rbB_B * YB[t - 9];
        basw[(2 * t + h_) * BAS_STRIDE + a_] = f16bits(v);
    }
    blo = *(const f16x4*)&basw[offB0]; bhi = *(const f16x4*)&basw[offB0 + 4];
    const f16x8 BfB0 = __builtin_shufflevector(blo, bhi, 0, 1, 2, 3, 4, 5, 6, 7);
    blo = *(const f16x4*)&basw[offB1]; bhi = *(const f16x4*)&basw[offB1 + 4];
    const f16x8 BfB1 = __builtin_shufflevector(blo, bhi, 0, 1, 2, 3, 4, 5, 6, 7);
    blo = *(const f16x4*)&basw[offB2]; bhi = *(const f16x4*)&basw[offB2 + 4];
    const f16x8 BfB2 = __builtin_shufflevector(blo, bhi, 0, 1, 2, 3, 4, 5, 6, 7);

    #pragma unroll
    for (int j4 = 0; j4 < 4; ++j4) {
        afB0.u[j4] = __builtin_amdgcn_perm(gB[2 * j4 + 1], gB[2 * j4], 0x05040100u);
        afB1.u[j4] = __builtin_amdgcn_perm(gB[2 * j4 + 1], gB[2 * j4], 0x07060302u);
    }
    __builtin_amdgcn_s_setprio(1);
    f32x4 DB00 = __builtin_amdgcn_mfma_f32_16x16x32_f16(afB0.v, BfB0, z4, 0, 0, 0);
    f32x4 DB01 = __builtin_amdgcn_mfma_f32_16x16x32_f16(afB0.v, BfB1, z4, 0, 0, 0);
    f32x4 DB02 = __builtin_amdgcn_mfma_f32_16x16x32_f16(afB0.v, BfB2, z4, 0, 0, 0);
    f32x4 DB10 = __builtin_amdgcn_mfma_f32_16x16x32_f16(afB1.v, BfB0, z4, 0, 0, 0);
    f32x4 DB11 = __builtin_amdgcn_mfma_f32_16x16x32_f16(afB1.v, BfB1, z4, 0, 0, 0);
    f32x4 DB12 = __builtin_amdgcn_mfma_f32_16x16x32_f16(afB1.v, BfB2, z4, 0, 0, 0);
    __builtin_amdgcn_s_setprio(0);

    // ---- D -> Mb[k'][p][c]: reg pairs = consecutive c -> single b32 writes ----
    {
        const int rowpA = pA * 36 + (q << 2);
        const int a0 = l15 * 580 + rowpA;          // nt=0
        const int a1 = (16 + l15) * 580 + rowpA;   // nt=1
        *(u32*)&Mb_s[a0]      = pk16(DA00[0], DA00[1]);
        *(u32*)&Mb_s[a0 + 2]  = pk16(DA00[2], DA00[3]);
        *(u32*)&Mb_s[a0 + 16] = pk16(DA10[0], DA10[1]);
        *(u32*)&Mb_s[a0 + 18] = pk16(DA10[2], DA10[3]);
        *(u32*)&Mb_s[a1]      = pk16(DA01[0], DA01[1]);
        *(u32*)&Mb_s[a1 + 2]  = pk16(DA01[2], DA01[3]);
        *(u32*)&Mb_s[a1 + 16] = pk16(DA11[0], DA11[1]);
        *(u32*)&Mb_s[a1 + 18] = pk16(DA11[2], DA11[3]);
        const int rowpB = pB * 36 + (q << 2);
        const int c0 = l15 * 580 + rowpB;
        const int c1 = (16 + l15) * 580 + rowpB;
        *(u32*)&Mb_s[c0]      = pk16(DB00[0], DB00[1]);
        *(u32*)&Mb_s[c0 + 2]  = pk16(DB00[2], DB00[3]);
        *(u32*)&Mb_s[c0 + 16] = pk16(DB10[0], DB10[1]);
        *(u32*)&Mb_s[c0 + 18] = pk16(DB10[2], DB10[3]);
        *(u32*)&Mb_s[c1]      = pk16(DB01[0], DB01[1]);
        *(u32*)&Mb_s[c1 + 2]  = pk16(DB01[2], DB01[3]);
        *(u32*)&Mb_s[c1 + 16] = pk16(DB11[0], DB11[1]);
        *(u32*)&Mb_s[c1 + 18] = pk16(DB11[2], DB11[3]);
        if (l15 < 4) {   // nt=2: k' = 32..35
            const int a2 = (32 + l15) * 580 + rowpA;
            *(u32*)&Mb_s[a2]      = pk16(DA02[0], DA02[1]);
            *(u32*)&Mb_s[a2 + 2]  = pk16(DA02[2], DA02[3]);
            *(u32*)&Mb_s[a2 + 16] = pk16(DA12[0], DA12[1]);
            *(u32*)&Mb_s[a2 + 18] = pk16(DA12[2], DA12[3]);
            const int c2 = (32 + l15) * 580 + rowpB;
            *(u32*)&Mb_s[c2]      = pk16(DB02[0], DB02[1]);
            *(u32*)&Mb_s[c2 + 2]  = pk16(DB02[2], DB02[3]);
            *(u32*)&Mb_s[c2 + 16] = pk16(DB12[0], DB12[1]);
            *(u32*)&Mb_s[c2 + 18] = pk16(DB12[2], DB12[3]);
        }
    }
    __syncthreads();

    // ============ Phase 2: pure LDS + MFMA, dual accumulator chains ============
    {
        f32x4 accE = {0.0f, 0.0f, 0.0f, 0.0f};
        f32x4 accO = {0.0f, 0.0f, 0.0f, 0.0f};
        #define P2_STEP(I, WF, ACC)                                                  \
        {                                                                            \
            const int mbase = (kt0 + I) * 580 + l15 * 36 + (q << 3);                 \
            const f16x4 mlo = *(const f16x4*)&Mb_s[mbase];                           \
            const f16x4 mhi = *(const f16x4*)&Mb_s[mbase + 4];                       \
            const f16x8 bf  = __builtin_shufflevector(mlo, mhi, 0,1,2,3,4,5,6,7);    \
            ACC = __builtin_amdgcn_mfma_f32_16x16x32_f16(WF, bf, ACC, 0, 0, 0);      \
        }
        __builtin_amdgcn_s_setprio(1);
        P2_STEP(0, wf0, accE) P2_STEP(1, wf1, accO) P2_STEP(2, wf2, accE)
        P2_STEP(3, wf3, accO) P2_STEP(4, wf4, accE) P2_STEP(5, wf5, accO)
        P2_STEP(6, wf6, accE) P2_STEP(7, wf7, accO) P2_STEP(8, wf8, accE)
        __builtin_amdgcn_s_setprio(0);
        #undef P2_STEP
        accE[0] += accO[0]; accE[1] += accO[1]; accE[2] += accO[2]; accE[3] += accO[3];
        *(f32x4*)&Cp[(w * 64 + lane) * 4] = accE;   // dedicated buffer
    }
    __syncthreads();

    // ---- epilogue reduce: ALL 8 waves; w encodes (dt2 = w>>2, rr = w&3) ----
    {
        const int dt2 = w >> 2;
        const int rr  = w & 3;
        float s = Cp[((dt2 * 4 + 0) * 64 + lane) * 4 + rr];
        #pragma unroll
        for (int rphase = 1; rphase < 4; ++rphase) {
            s += Cp[((dt2 * 4 + rphase) * 64 + lane) * 4 + rr];
        }
        const int drow = dt2 * 16 + ((lane >> 4) << 2) + rr;   // D row = (lane>>4)*4 + reg
        const int col  = b0 + (lane & 15);
        out[(((n_ << 5) + drow) << 13) + col] = s;
    }
}

extern "C" void kernel_launch(void* const* d_in, const int* in_sizes, int n_in,
                              void* d_out, int out_size, void* d_ws, size_t ws_size,
                              hipStream_t stream)
{
    const float* inp    = (const float*)d_in[0];
    const float* coords = (const float*)d_in[1];
    const float* rmask  = (const float*)d_in[2];
    const float* W      = (const float*)d_in[3];
    const int*   neigh  = (const int*)d_in[4];
    float*       outp   = (float*)d_out;

    unsigned short* inp_t16 = (unsigned short*)d_ws;                        // 2 MB f16 (interleaved)
    unsigned short* Wfrag   = (unsigned short*)((char*)d_ws + (2u << 20));  // 73.7 KB
    float*          coords4 = (float*)((char*)d_ws + (4u << 20));           // 512 KB float4

    prep_kernel<<<1296, 256, 0, stream>>>(inp, W, coords, inp_t16, Wfrag, coords4);
    se3_main<<<2048, 512, 0, stream>>>(inp_t16, coords4, rmask, neigh, Wfrag, outp);
}